// Round 3
// baseline (122.810 us; speedup 1.0000x reference)
//
#include <hip/hip_runtime.h>

// OESNN_SEPhIA_MultiTiled2: 32-step recurrent SNN, B=8192.
// R3: (a) weights staged via LDS so in-loop remat (if any) is cheap ds_read
// instead of 200-cyc global loads (R2's VGPR=120 proved global weight arrays
// were not kept resident); (b) 16 lanes per batch element -> 2048 waves =
// 2 waves/SIMD. Lane sub: primary layer-0 channel cA = (sub>>3)*9 + (sub&7);
// lanes 0 and 8 also own channels 8 / 17. Layer-1: lane owns column s=sub,
// even/odd combined via shfl_xor(1). Numerics op-for-op identical to the
// passing R2 kernel.

namespace {
constexpr int Tn = 32;
constexpr int Bn = 8192;
constexpr int O_PW = 0;                       // spks0 (= pw0) [T,B,18]
constexpr int O_S1 = Tn * Bn * 18;            // spks1 [T,B,8]
constexpr int O_M0 = O_S1 + Tn * Bn * 8;      // mems0 [T,B,18]
constexpr int O_M1 = O_M0 + Tn * Bn * 18;     // mems1 [T,B,8]
constexpr int LDS_W1 = 648;                   // w0: 18ch x 36 floats
constexpr int LDS_TOT = 648 + 16 * 20;        // w1: 16 cols x 20 (18+2 pad)
}

__global__ __launch_bounds__(256, 2)
void oesnn_kernel(const float* __restrict__ x_in,
                  const float* __restrict__ W0g,   // [2,18,18*2]
                  const float* __restrict__ d0g,   // [2,9]
                  const float* __restrict__ W1g,   // [1,18,16]
                  const float* __restrict__ d1g,   // [1,8]
                  const float* __restrict__ peakg, // [36]
                  float* __restrict__ out)
{
    __shared__ float lds[LDS_TOT];

    // ---- stage weights into LDS (channel-contiguous, interleaved e/o) ----
    for (int idx = threadIdx.x; idx < LDS_TOT; idx += 256) {
        float v;
        if (idx < LDS_W1) {
            const int c  = idx / 36, r = idx - c * 36;
            const int tl = c / 9,  jc = c - tl * 9;
            const int w  = r >> 1, par = r & 1;
            v = W0g[(tl * 18 + w) * 18 + 2 * jc + par];
        } else {
            const int k = idx - LDS_W1;
            const int s = k / 20, w = k - s * 20;
            v = (w < 18) ? W1g[w * 16 + s] : 0.0f;
        }
        lds[idx] = v;
    }
    __syncthreads();

    const int lt   = threadIdx.x & 63;
    const int tid  = blockIdx.x * 256 + threadIdx.x;
    const int b    = tid >> 4;                // batch element
    const int sub  = tid & 15;                // lane within batch group
    const int tl   = sub >> 3;                // layer-0 tile (0/1)
    const int q    = sub & 7;
    const int cA   = tl * 9 + q;              // primary channel (0..7, 9..16)
    const bool has2 = (q == 0);
    const int cB   = has2 ? (tl * 9 + 8) : cA; // extra channel 8 / 17 (dup else)

    // ---- per-lane constants: d0, d1, pw on/off tables ----
    const float dd0A = d0g[cA];
    const float dd0B = d0g[cB];
    const float dd1  = d1g[sub >> 1];

    float ponA, poffA, ponB, poffB;
    {
        #pragma unroll
        for (int which = 0; which < 2; ++which) {
            const int c = which ? cB : cA;
            const float wl    = 1550.0f + 0.8f * (float)c;
            const float halfw = 0.5f * (wl * 1e3f / 15000.0f);
            const float amp   = sqrtf((exp10f(peakg[c] / 10.0f) / 1000.0f) * 1e6f);
            const float lr0 = 0.1f * amp;
            const float a0  = sqrtf(lr0 * lr0);
            const float poff = a0 * a0;
            const float delta = -250.0f / halfw;
            const float den = fmaf(delta, delta, 1.0f);
            const float qr  = fmaf(delta, delta, 0.1f) / den;
            const float qi  = (delta - 0.1f * delta) / den;
            const float lr = qr * amp, li = qi * amp;
            const float a  = sqrtf(fmaf(lr, lr, li * li));
            const float pon = a * a;
            if (which) { ponB = pon; poffB = poff; }
            else       { ponA = pon; poffA = poff; }
        }
    }

    // ---- weights: LDS -> register arrays (cheap to remat if compiler sinks) ----
    float4 wA[9], wB[9];
    #pragma unroll
    for (int k = 0; k < 9; ++k) {
        wA[k] = ((const float4*)(lds + cA * 36))[k];
        wB[k] = ((const float4*)(lds + cB * 36))[k];
    }
    float4 w1a[4];
    float2 w1b;
    #pragma unroll
    for (int k = 0; k < 4; ++k)
        w1a[k] = ((const float4*)(lds + LDS_W1 + sub * 20))[k];
    w1b = ((const float2*)(lds + LDS_W1 + sub * 20))[8];

    // ---- state & pointers ----
    float mA = 0.f, mB = 0.f, m1 = 0.f;
    const float* xp = x_in + (size_t)b * 36 + tl * 18;
    float* opwA = out + O_PW + (size_t)b * 18 + cA;
    float* om0A = out + O_M0 + (size_t)b * 18 + cA;
    float* opwB = out + O_PW + (size_t)b * 18 + cB;
    float* om0B = out + O_M0 + (size_t)b * 18 + cB;
    float* os1  = out + O_S1 + (size_t)b * 8 + (sub >> 1);
    float* om1  = out + O_M1 + (size_t)b * 8 + (sub >> 1);

    // prefetch t=0 inputs (this tile's 18 floats = 9x float2, 8B-aligned)
    float2 xv[9];
    #pragma unroll
    for (int k = 0; k < 9; ++k) xv[k] = *(const float2*)(xp + 2 * k);

    const int basel = lt & ~15;

    #pragma unroll 1
    for (int t = 0; t < Tn; ++t) {
        // p = x * 1e-4 (reference order: scale first, then matvec)
        float px[18];
        #pragma unroll
        for (int k = 0; k < 9; ++k) {
            px[2 * k]     = xv[k].x * 1e-4f;
            px[2 * k + 1] = xv[k].y * 1e-4f;
        }
        xp += Bn * 36;
        if (t < Tn - 1) {
            #pragma unroll
            for (int k = 0; k < 9; ++k) xv[k] = *(const float2*)(xp + 2 * k);
        }

        // ---- layer 0: even/odd sums, balanced PD, LIF, MRR power ----
        float seA = 0.f, soA = 0.f, seB = 0.f, soB = 0.f;
        #pragma unroll
        for (int k = 0; k < 9; ++k) {
            const float4 fa = wA[k];
            seA = fmaf(px[2 * k],     fa.x, seA);
            soA = fmaf(px[2 * k],     fa.y, soA);
            seA = fmaf(px[2 * k + 1], fa.z, seA);
            soA = fmaf(px[2 * k + 1], fa.w, soA);
            const float4 fb = wB[k];
            seB = fmaf(px[2 * k],     fb.x, seB);
            soB = fmaf(px[2 * k],     fb.y, soB);
            seB = fmaf(px[2 * k + 1], fb.z, seB);
            soB = fmaf(px[2 * k + 1], fb.w, soB);
        }
        const float c0A = (seA - soA) * dd0A;
        const float m2A = (mA > 0.55f) ? 0.0f : fmaf(0.95f, mA, c0A);
        mA = m2A;
        const float pwA = (m2A > 0.55f) ? ponA : poffA;

        const float c0B = (seB - soB) * dd0B;
        const float m2B = (mB > 0.55f) ? 0.0f : fmaf(0.95f, mB, c0B);
        mB = m2B;
        const float pwB = (m2B > 0.55f) ? ponB : poffB;

        opwA[0] = pwA;
        om0A[0] = m2A;
        if (has2) {
            opwB[0] = pwB;
            om0B[0] = m2B;
        }

        // ---- cross-lane gather of all 18 pw values ----
        float pwall[18];
        #pragma unroll
        for (int c = 0; c < 18; ++c) {
            const int tlc = c / 9, jc = c - 9 * tlc;
            const int own = basel + tlc * 8 + ((jc == 8) ? 0 : jc);
            pwall[c] = __shfl((jc == 8) ? pwB : pwA, own, 64);
        }

        // ---- layer 1: this lane's column s=sub, ascending w ----
        float i1 = 0.f;
        #pragma unroll
        for (int k = 0; k < 4; ++k) {
            const float4 f = w1a[k];
            i1 = fmaf(pwall[4 * k],     f.x, i1);
            i1 = fmaf(pwall[4 * k + 1], f.y, i1);
            i1 = fmaf(pwall[4 * k + 2], f.z, i1);
            i1 = fmaf(pwall[4 * k + 3], f.w, i1);
        }
        i1 = fmaf(pwall[16], w1b.x, i1);
        i1 = fmaf(pwall[17], w1b.y, i1);

        const float i1p = __shfl_xor(i1, 1, 64);   // partner column
        const float c1  = (i1 - i1p) * dd1;        // valid on even lanes
        const float m2  = (m1 > 0.25f) ? 0.0f : fmaf(0.95f, m1, c1);
        m1 = m2;
        if (!(sub & 1)) {
            *os1 = (m2 > 0.25f) ? 1.0f : 0.0f;     // 32 consecutive dwords/wave
            *om1 = m2;
        }

        opwA += Bn * 18; om0A += Bn * 18;
        opwB += Bn * 18; om0B += Bn * 18;
        os1  += Bn * 8;  om1  += Bn * 8;
    }
}

extern "C" void kernel_launch(void* const* d_in, const int* in_sizes, int n_in,
                              void* d_out, int out_size, void* d_ws, size_t ws_size,
                              hipStream_t stream) {
    (void)in_sizes; (void)n_in; (void)out_size; (void)d_ws; (void)ws_size;
    const float* x  = (const float*)d_in[0];
    const float* W0 = (const float*)d_in[1];
    const float* d0 = (const float*)d_in[2];
    const float* W1 = (const float*)d_in[3];
    const float* d1 = (const float*)d_in[4];
    const float* pk = (const float*)d_in[5];
    float* out = (float*)d_out;

    dim3 grid(Bn * 16 / 256), block(256);
    hipLaunchKernelGGL(oesnn_kernel, grid, block, 0, stream,
                       x, W0, d0, W1, d1, pk, out);
}

// Round 4
// 122.408 us; speedup vs baseline: 1.0033x; 1.0033x over previous
//
#include <hip/hip_runtime.h>

// OESNN_SEPhIA_MultiTiled2: 32-step recurrent SNN, B=8192.
// R4: same geometry/arithmetic as R3 (16 lanes/batch, 2048 waves = 2/SIMD),
// but weights are FORCED register-resident:
//   - amdgpu_waves_per_eu(2,2): allocator targets exactly 2 waves/SIMD
//     (256-VGPR cap) instead of trimming toward 4+ waves.
//   - asm volatile("" : "+v") pins on every weight value: opaque defs cannot
//     be rematerialized/sunk into the t-loop (R2/R3 evidence: VGPR=120/92
//     with in-loop weight refetch saturating the per-CU L1/LDS pipe at
//     ~2k cyc/iter -> the invariant ~44 us).
// No LDS at all (no barrier, no bank conflicts). In-loop memory = x prefetch
// + output stores only. Numerics op-for-op identical to the passing R3 run.

namespace {
constexpr int Tn = 32;
constexpr int Bn = 8192;
constexpr int O_PW = 0;                       // spks0 (= pw0) [T,B,18]
constexpr int O_S1 = Tn * Bn * 18;            // spks1 [T,B,8]
constexpr int O_M0 = O_S1 + Tn * Bn * 8;      // mems0 [T,B,18]
constexpr int O_M1 = O_M0 + Tn * Bn * 18;     // mems1 [T,B,8]
}

__global__ __attribute__((amdgpu_flat_work_group_size(256, 256),
                          amdgpu_waves_per_eu(2, 2)))
void oesnn_kernel(const float* __restrict__ x_in,
                  const float* __restrict__ W0g,   // [2,18,18*2]
                  const float* __restrict__ d0g,   // [2,9]
                  const float* __restrict__ W1g,   // [1,18,16]
                  const float* __restrict__ d1g,   // [1,8]
                  const float* __restrict__ peakg, // [36]
                  float* __restrict__ out)
{
    const int lt   = threadIdx.x & 63;
    const int tid  = blockIdx.x * 256 + threadIdx.x;
    const int b    = tid >> 4;                // batch element
    const int sub  = tid & 15;                // lane within batch group
    const int tl   = sub >> 3;                // layer-0 tile (0/1)
    const int q    = sub & 7;
    const int cA   = tl * 9 + q;              // primary channel (0..7, 9..16)
    const bool has2 = (q == 0);
    const int cB   = has2 ? (tl * 9 + 8) : cA; // extra channel 8/17 (dup else)
    const int jA   = q;                        // in-tile index of cA
    const int jB   = has2 ? 8 : q;             // in-tile index of cB

    // ---- one-time weight load straight from global, then PIN in VGPRs ----
    float wA[36], wB[36];                      // [2w]=even col, [2w+1]=odd col
    #pragma unroll
    for (int w = 0; w < 18; ++w) {
        const float2 pa = *(const float2*)(W0g + (tl * 18 + w) * 18 + 2 * jA);
        wA[2 * w] = pa.x;  wA[2 * w + 1] = pa.y;
        const float2 pb = *(const float2*)(W0g + (tl * 18 + w) * 18 + 2 * jB);
        wB[2 * w] = pb.x;  wB[2 * w + 1] = pb.y;
    }
    float w1[18];                              // layer-1 column s = sub
    #pragma unroll
    for (int w = 0; w < 18; ++w)
        w1[w] = W1g[w * 16 + sub];

    float dd0A = d0g[cA];
    float dd0B = d0g[cB];
    float dd1  = d1g[sub >> 1];

    float ponA, poffA, ponB, poffB;
    #pragma unroll
    for (int which = 0; which < 2; ++which) {
        const int c = which ? cB : cA;
        const float wl    = 1550.0f + 0.8f * (float)c;
        const float halfw = 0.5f * (wl * 1e3f / 15000.0f);
        const float amp   = sqrtf((exp10f(peakg[c] / 10.0f) / 1000.0f) * 1e6f);
        const float lr0 = 0.1f * amp;
        const float a0  = sqrtf(lr0 * lr0);
        const float poff = a0 * a0;
        const float delta = -250.0f / halfw;
        const float den = fmaf(delta, delta, 1.0f);
        const float qr  = fmaf(delta, delta, 0.1f) / den;
        const float qi  = (delta - 0.1f * delta) / den;
        const float lr = qr * amp, li = qi * amp;
        const float a  = sqrtf(fmaf(lr, lr, li * li));
        const float pon = a * a;
        if (which) { ponB = pon; poffB = poff; }
        else       { ponA = pon; poffA = poff; }
    }

    // Pin everything loop-invariant: opaque defs can't be remat'd/sunk.
    #pragma unroll
    for (int i = 0; i < 36; ++i) { asm volatile("" : "+v"(wA[i])); }
    #pragma unroll
    for (int i = 0; i < 36; ++i) { asm volatile("" : "+v"(wB[i])); }
    #pragma unroll
    for (int i = 0; i < 18; ++i) { asm volatile("" : "+v"(w1[i])); }
    asm volatile("" : "+v"(dd0A), "+v"(dd0B), "+v"(dd1));
    asm volatile("" : "+v"(ponA), "+v"(poffA), "+v"(ponB), "+v"(poffB));

    // ---- state & pointers ----
    float mA = 0.f, mB = 0.f, m1 = 0.f;
    const float* xp = x_in + (size_t)b * 36 + tl * 18;
    float* opwA = out + O_PW + (size_t)b * 18 + cA;
    float* om0A = out + O_M0 + (size_t)b * 18 + cA;
    float* opwB = out + O_PW + (size_t)b * 18 + cB;
    float* om0B = out + O_M0 + (size_t)b * 18 + cB;
    float* os1  = out + O_S1 + (size_t)b * 8 + (sub >> 1);
    float* om1  = out + O_M1 + (size_t)b * 8 + (sub >> 1);

    // prefetch t=0 inputs (this tile's 18 floats = 9x float2, 8B-aligned)
    float2 xv[9];
    #pragma unroll
    for (int k = 0; k < 9; ++k) xv[k] = *(const float2*)(xp + 2 * k);

    const int basel = lt & ~15;

    #pragma unroll 1
    for (int t = 0; t < Tn; ++t) {
        // p = x * 1e-4 (reference order: scale first, then matvec)
        float px[18];
        #pragma unroll
        for (int k = 0; k < 9; ++k) {
            px[2 * k]     = xv[k].x * 1e-4f;
            px[2 * k + 1] = xv[k].y * 1e-4f;
        }
        xp += Bn * 36;
        if (t < Tn - 1) {
            #pragma unroll
            for (int k = 0; k < 9; ++k) xv[k] = *(const float2*)(xp + 2 * k);
        }

        // ---- layer 0: even/odd sums, balanced PD, LIF, MRR power ----
        float seA = 0.f, soA = 0.f, seB = 0.f, soB = 0.f;
        #pragma unroll
        for (int w = 0; w < 18; ++w) {
            seA = fmaf(px[w], wA[2 * w],     seA);
            soA = fmaf(px[w], wA[2 * w + 1], soA);
            seB = fmaf(px[w], wB[2 * w],     seB);
            soB = fmaf(px[w], wB[2 * w + 1], soB);
        }
        const float c0A = (seA - soA) * dd0A;
        const float m2A = (mA > 0.55f) ? 0.0f : fmaf(0.95f, mA, c0A);
        mA = m2A;
        const float pwA = (m2A > 0.55f) ? ponA : poffA;

        const float c0B = (seB - soB) * dd0B;
        const float m2B = (mB > 0.55f) ? 0.0f : fmaf(0.95f, mB, c0B);
        mB = m2B;
        const float pwB = (m2B > 0.55f) ? ponB : poffB;

        opwA[0] = pwA;
        om0A[0] = m2A;
        if (has2) {
            opwB[0] = pwB;
            om0B[0] = m2B;
        }

        // ---- cross-lane gather of all 18 pw values ----
        float pwall[18];
        #pragma unroll
        for (int c = 0; c < 18; ++c) {
            const int tlc = c / 9, jc = c - 9 * tlc;
            const int own = basel + tlc * 8 + ((jc == 8) ? 0 : jc);
            pwall[c] = __shfl((jc == 8) ? pwB : pwA, own, 64);
        }

        // ---- layer 1: this lane's column s=sub, ascending w ----
        float i1 = 0.f;
        #pragma unroll
        for (int w = 0; w < 18; ++w)
            i1 = fmaf(pwall[w], w1[w], i1);

        const float i1p = __shfl_xor(i1, 1, 64);   // partner column
        const float c1  = (i1 - i1p) * dd1;        // valid on even lanes
        const float m2  = (m1 > 0.25f) ? 0.0f : fmaf(0.95f, m1, c1);
        m1 = m2;
        if (!(sub & 1)) {
            *os1 = (m2 > 0.25f) ? 1.0f : 0.0f;     // 32 consecutive dwords/wave
            *om1 = m2;
        }

        opwA += Bn * 18; om0A += Bn * 18;
        opwB += Bn * 18; om0B += Bn * 18;
        os1  += Bn * 8;  om1  += Bn * 8;
    }
}

extern "C" void kernel_launch(void* const* d_in, const int* in_sizes, int n_in,
                              void* d_out, int out_size, void* d_ws, size_t ws_size,
                              hipStream_t stream) {
    (void)in_sizes; (void)n_in; (void)out_size; (void)d_ws; (void)ws_size;
    const float* x  = (const float*)d_in[0];
    const float* W0 = (const float*)d_in[1];
    const float* d0 = (const float*)d_in[2];
    const float* W1 = (const float*)d_in[3];
    const float* d1 = (const float*)d_in[4];
    const float* pk = (const float*)d_in[5];
    float* out = (float*)d_out;

    dim3 grid(Bn * 16 / 256), block(256);
    hipLaunchKernelGGL(oesnn_kernel, grid, block, 0, stream,
                       x, W0, d0, W1, d1, pk, out);
}